// Round 2
// baseline (268.609 us; speedup 1.0000x reference)
//
#include <hip/hip_runtime.h>

// y = x @ (W * M)^T with M = identity -> y[b,d] = x[b,d] * W[d,d]*M[d,d].
// HBM-bound elementwise scale: 134 MB read + 134 MB write, floor ~40 us @ 6.7 TB/s.
//
// Structure:
//   k1: extract masked diagonal into d_ws (2048 strided loads, ~1-2 us)
//   k2: persistent-thread scale. 2048 blocks x 256 thr = 524288 threads =
//       512 col-groups x 1024 rows. Each thread keeps its 4 diag values in
//       registers and loops 16 row-strides (fully unrolled -> 16 independent
//       16B loads in flight). 32 waves/CU occupancy, coalesced 16 B/lane.

#define DDIM 2048
#define BDIM 16384
#define COLG (DDIM / 4)        // 512 column groups of float4
#define ROWS_PER_PASS 1024     // 524288 threads / 512 colgroups
#define NPASS (BDIM / ROWS_PER_PASS)  // 16

__global__ void extract_diag_kernel(const float* __restrict__ W,
                                    const float* __restrict__ M,
                                    float* __restrict__ diag) {
    int d = blockIdx.x * blockDim.x + threadIdx.x;
    if (d < DDIM) {
        size_t idx = (size_t)d * (DDIM + 1);
        diag[d] = W[idx] * M[idx];
    }
}

__global__ __launch_bounds__(256) void diag_scale_kernel(
        const float* __restrict__ x,
        const float* __restrict__ diag,
        float* __restrict__ out) {
    int t = blockIdx.x * 256 + threadIdx.x;   // 0 .. 524287
    int cg  = t & (COLG - 1);                 // fixed column group
    int row = t >> 9;                         // 0 .. 1023

    // Diag scale for this thread's 4 columns: loaded ONCE, kept in registers.
    float4 w = *reinterpret_cast<const float4*>(diag + cg * 4);

    size_t base = (size_t)row * DDIM + (size_t)cg * 4;
    const size_t step = (size_t)ROWS_PER_PASS * DDIM;

#pragma unroll
    for (int i = 0; i < NPASS; ++i) {
        float4 xv = *reinterpret_cast<const float4*>(x + base);
        float4 o;
        o.x = xv.x * w.x;
        o.y = xv.y * w.y;
        o.z = xv.z * w.z;
        o.w = xv.w * w.w;
        *reinterpret_cast<float4*>(out + base) = o;
        base += step;
    }
}

extern "C" void kernel_launch(void* const* d_in, const int* in_sizes, int n_in,
                              void* d_out, int out_size, void* d_ws, size_t ws_size,
                              hipStream_t stream) {
    const float* x = (const float*)d_in[0];
    const float* W = (const float*)d_in[1];
    const float* M = (const float*)d_in[2];
    float* out = (float*)d_out;
    float* diag = (float*)d_ws;  // 8 KB scratch

    extract_diag_kernel<<<DDIM / 256, 256, 0, stream>>>(W, M, diag);

    // 2048 blocks x 256 threads: 8 blocks/CU on 256 CUs, 32 waves/CU.
    diag_scale_kernel<<<2048, 256, 0, stream>>>(x, diag, out);
}

// Round 4
// 242.964 us; speedup vs baseline: 1.1056x; 1.1056x over previous
//
#include <hip/hip_runtime.h>

// y = x @ (W * M)^T with M = identity -> y[b,d] = x[b,d] * W[d,d]*M[d,d].
// HBM-bound elementwise scale: 134 MB read + 134 MB write, floor ~40 us.
//
// R2 lesson: long serial unrolled loops with vmcnt(0)-per-iter collapse MLP
// (2.1 TB/s). This round: one-shot mapping, 4 independent float4 chunks per
// thread offset by blockDim (all coalesced), loads batched before stores,
// nontemporal stores (native clang vector type -- HIP float4 is rejected by
// the builtin) to stream y past L2/L3 and keep x L3-resident.

#define DDIM 2048
#define BDIM 16384
#define CHUNKS 4
#define BLOCK 256

typedef float vfloat4 __attribute__((ext_vector_type(4)));

__global__ void extract_diag_kernel(const float* __restrict__ W,
                                    const float* __restrict__ M,
                                    float* __restrict__ diag) {
    int d = blockIdx.x * blockDim.x + threadIdx.x;
    if (d < DDIM) {
        size_t idx = (size_t)d * (DDIM + 1);
        diag[d] = W[idx] * M[idx];
    }
}

__global__ __launch_bounds__(BLOCK) void diag_scale_kernel(
        const float* __restrict__ x,
        const float* __restrict__ diag,
        float* __restrict__ out) {
    // Flat float4 index space: B*D/4 = 8,388,608 float4s.
    // Block covers CHUNKS*BLOCK contiguous float4s; chunk c at +c*BLOCK.
    const size_t base4 = (size_t)blockIdx.x * (BLOCK * CHUNKS) + threadIdx.x;

    // Column group repeats mod 512 (D/4). Block base is a multiple of 1024,
    // so colgroup(c) = (tid + c*256) & 511 -> only 2 distinct diag vfloat4s.
    const int cg0 = threadIdx.x;          // chunks 0,2
    const int cg1 = threadIdx.x + BLOCK;  // chunks 1,3
    vfloat4 w0 = *reinterpret_cast<const vfloat4*>(diag + cg0 * 4);
    vfloat4 w1 = *reinterpret_cast<const vfloat4*>(diag + cg1 * 4);

    // Issue all 4 x-loads before any store (independent -> 4 in flight).
    vfloat4 xv[CHUNKS];
#pragma unroll
    for (int c = 0; c < CHUNKS; ++c) {
        xv[c] = *reinterpret_cast<const vfloat4*>(x + (base4 + (size_t)c * BLOCK) * 4);
    }

#pragma unroll
    for (int c = 0; c < CHUNKS; ++c) {
        const vfloat4 w = (c & 1) ? w1 : w0;
        vfloat4 o = xv[c] * w;   // elementwise on native vector type
        __builtin_nontemporal_store(
            o, reinterpret_cast<vfloat4*>(out + (base4 + (size_t)c * BLOCK) * 4));
    }
}

extern "C" void kernel_launch(void* const* d_in, const int* in_sizes, int n_in,
                              void* d_out, int out_size, void* d_ws, size_t ws_size,
                              hipStream_t stream) {
    const float* x = (const float*)d_in[0];
    const float* W = (const float*)d_in[1];
    const float* M = (const float*)d_in[2];
    float* out = (float*)d_out;
    float* diag = (float*)d_ws;  // 8 KB scratch

    extract_diag_kernel<<<DDIM / 256, 256, 0, stream>>>(W, M, diag);

    // 8,388,608 float4s / (256 thr * 4 chunks) = 8192 blocks (32/CU).
    const int grid = (BDIM * DDIM / 4) / (BLOCK * CHUNKS);
    diag_scale_kernel<<<grid, BLOCK, 0, stream>>>(x, diag, out);
}